// Round 1
// baseline (487.058 us; speedup 1.0000x reference)
//
#include <hip/hip_runtime.h>
#include <stdint.h>

#define BB 16
#define HH 512
#define WW 512
#define HW (HH*WW)
#define NB 256
#define MARGIN 12

// region indices: 0=skin(ch1), 1=ch4, 2=lip(ch0), 3=eye(m_se)

__device__ __forceinline__ float denorm255(float x) {
    return fminf(fmaxf((x + 1.0f) * 0.5f, 0.0f), 1.0f) * 255.0f;
}
__device__ __forceinline__ float renorm_lut(int t) {
    return ((float)t / 255.0f) * 2.0f - 1.0f;
}

// ---- Pass A1: horizontal 25-tap max of (mask[2]+mask[3]) for both sides ----
__global__ void __launch_bounds__(256) rowmax_kernel(
    const float* __restrict__ ms, const float* __restrict__ mr,
    uint8_t* __restrict__ tmp)
{
    int row  = blockIdx.x;            // 0 .. 2*BB*HH-1
    int side = row / (BB * HH);
    int bh   = row % (BB * HH);
    int b = bh / HH, y = bh % HH;
    const float* base = (side == 0 ? ms : mr);
    const float* m = base + ((size_t)b * 5 + 2) * HW + (size_t)y * WW;
    __shared__ uint8_t s[WW];
    for (int x = threadIdx.x; x < WW; x += blockDim.x) {
        float v = m[x] + m[HW + x];   // ch2 + ch3, values 0/1/2
        s[x] = (uint8_t)v;
    }
    __syncthreads();
    uint8_t* o = tmp + ((size_t)side * BB + b) * HW + (size_t)y * WW;
    for (int x = threadIdx.x; x < WW; x += blockDim.x) {
        int lo = max(x - MARGIN, 0), hi = min(x + MARGIN, WW - 1);
        int mx = 0;
        for (int k = lo; k <= hi; k++) mx = max(mx, (int)s[k]);
        o[x] = (uint8_t)mx;
    }
}

// ---- Pass A2: vertical 25-tap max, multiply by mask[1] -> m_se / m_re ----
__global__ void __launch_bounds__(256) colmax_kernel(
    const float* __restrict__ ms, const float* __restrict__ mr,
    const uint8_t* __restrict__ tmp, uint8_t* __restrict__ mse)
{
    int row  = blockIdx.x;
    int side = row / (BB * HH);
    int bh   = row % (BB * HH);
    int b = bh / HH, y = bh % HH;
    const uint8_t* t = tmp + ((size_t)side * BB + b) * HW;
    const float* m1 = (side == 0 ? ms : mr) + ((size_t)b * 5 + 1) * HW + (size_t)y * WW;
    uint8_t* o = mse + ((size_t)side * BB + b) * HW + (size_t)y * WW;
    int lo = max(y - MARGIN, 0), hi = min(y + MARGIN, HH - 1);
    for (int x = threadIdx.x; x < WW; x += blockDim.x) {
        int mx = 0;
        for (int k = lo; k <= hi; k++) mx = max(mx, (int)t[(size_t)k * WW + x]);
        float mm = m1[x];                 // exactly 0.0 or 1.0
        o[x] = (uint8_t)((float)mx * mm); // 0,1,2
    }
}

// ---- Pass A3: horizontal 5-tap sum of m_se (src side only) ----
__global__ void __launch_bounds__(256) rowsum_kernel(
    const uint8_t* __restrict__ mse_src, uint8_t* __restrict__ tmp)
{
    int row = blockIdx.x;               // 0 .. BB*HH-1
    int b = row / HH, y = row % HH;
    const uint8_t* m = mse_src + (size_t)b * HW + (size_t)y * WW;
    __shared__ uint8_t s[WW];
    for (int x = threadIdx.x; x < WW; x += blockDim.x) s[x] = m[x];
    __syncthreads();
    uint8_t* o = tmp + (size_t)row * WW;
    for (int x = threadIdx.x; x < WW; x += blockDim.x) {
        int lo = max(x - 2, 0), hi = min(x + 2, WW - 1);
        int sum = 0;
        for (int k = lo; k <= hi; k++) sum += s[k];
        o[x] = (uint8_t)sum;            // <= 10
    }
}

// ---- Pass A4: vertical 5-tap sum -> boxsum (<=50) ----
__global__ void __launch_bounds__(256) colsum_kernel(
    const uint8_t* __restrict__ tmp, uint8_t* __restrict__ mbs)
{
    int row = blockIdx.x;
    int b = row / HH, y = row % HH;
    int lo = max(y - 2, 0), hi = min(y + 2, HH - 1);
    const uint8_t* t = tmp + (size_t)b * HW;
    uint8_t* o = mbs + (size_t)row * WW;
    for (int x = threadIdx.x; x < WW; x += blockDim.x) {
        int s = 0;
        for (int k = lo; k <= hi; k++) s += t[(size_t)k * WW + x];
        o[x] = (uint8_t)s;
    }
}

// ---- Pass B: 12 weighted histograms per (batch, side) ----
__global__ void __launch_bounds__(256) hist_kernel(
    const float* __restrict__ src, const float* __restrict__ tgt,
    const float* __restrict__ ms, const float* __restrict__ mr,
    const uint8_t* __restrict__ mse, int* __restrict__ hist, int blocksPer)
{
    int bs  = blockIdx.x / blocksPer;   // b*2+side
    int blk = blockIdx.x % blocksPer;
    int b = bs >> 1, side = bs & 1;
    const float* img = (side == 0 ? src : tgt) + (size_t)b * 3 * HW;
    const float* msk = (side == 0 ? ms : mr) + (size_t)b * 5 * HW;
    const uint8_t* me = mse + ((size_t)side * BB + b) * HW;

    __shared__ int h[12 * NB];
    for (int i = threadIdx.x; i < 12 * NB; i += blockDim.x) h[i] = 0;
    __syncthreads();

    int stride = blocksPer * blockDim.x;
    for (int i = blk * blockDim.x + threadIdx.x; i < HW; i += stride) {
        float d0 = denorm255(img[i]);
        float d1 = denorm255(img[HW + i]);
        float d2 = denorm255(img[2 * HW + i]);
        float m1 = msk[HW + i];          // skin  (region 0)
        float m4 = msk[4 * HW + i];      //       (region 1)
        float m0 = msk[i];               // lip   (region 2)
        int  mei = me[i];                // eye   (region 3), 0/1/2
        if (m1 > 0.0f) {
            int w = (int)m1;
            atomicAdd(&h[(0 * 3 + 0) * NB + min((int)(d0 * m1), 255)], w);
            atomicAdd(&h[(0 * 3 + 1) * NB + min((int)(d1 * m1), 255)], w);
            atomicAdd(&h[(0 * 3 + 2) * NB + min((int)(d2 * m1), 255)], w);
        }
        if (m4 > 0.0f) {
            int w = (int)m4;
            atomicAdd(&h[(1 * 3 + 0) * NB + min((int)(d0 * m4), 255)], w);
            atomicAdd(&h[(1 * 3 + 1) * NB + min((int)(d1 * m4), 255)], w);
            atomicAdd(&h[(1 * 3 + 2) * NB + min((int)(d2 * m4), 255)], w);
        }
        if (m0 > 0.0f) {
            int w = (int)m0;
            atomicAdd(&h[(2 * 3 + 0) * NB + min((int)(d0 * m0), 255)], w);
            atomicAdd(&h[(2 * 3 + 1) * NB + min((int)(d1 * m0), 255)], w);
            atomicAdd(&h[(2 * 3 + 2) * NB + min((int)(d2 * m0), 255)], w);
        }
        if (mei > 0) {
            float fm = (float)mei;
            atomicAdd(&h[(3 * 3 + 0) * NB + min((int)(d0 * fm), 255)], mei);
            atomicAdd(&h[(3 * 3 + 1) * NB + min((int)(d1 * fm), 255)], mei);
            atomicAdd(&h[(3 * 3 + 2) * NB + min((int)(d2 * fm), 255)], mei);
        }
    }
    __syncthreads();
    int* gh = hist + (size_t)bs * 12 * NB;
    for (int i = threadIdx.x; i < 12 * NB; i += blockDim.x)
        if (h[i]) atomicAdd(&gh[i], h[i]);
}

// ---- Pass C: cdf + searchsorted -> 256-entry LUT per (b, region, channel) ----
__global__ void __launch_bounds__(NB) table_kernel(
    const int* __restrict__ hist, uint8_t* __restrict__ table)
{
    int idx = blockIdx.x;               // (b*4+rg)*3+c, 192 blocks
    int c = idx % 3; int rest = idx / 3; int rg = rest & 3; int b = rest >> 2;
    const int* hs = hist + ((size_t)((b * 2 + 0) * 4 + rg) * 3 + c) * NB;
    const int* hr = hist + ((size_t)((b * 2 + 1) * 4 + rg) * 3 + c) * NB;
    __shared__ int a[NB];
    __shared__ float cr[NB];
    int t = threadIdx.x;

    // inclusive scan of source histogram
    a[t] = hs[t];
    __syncthreads();
    for (int off = 1; off < NB; off <<= 1) {
        int v = (t >= off) ? a[t - off] : 0;
        __syncthreads();
        a[t] += v;
        __syncthreads();
    }
    int totS = a[NB - 1];
    int cumS = a[t];
    __syncthreads();

    // inclusive scan of reference histogram
    a[t] = hr[t];
    __syncthreads();
    for (int off = 1; off < NB; off <<= 1) {
        int v = (t >= off) ? a[t - off] : 0;
        __syncthreads();
        a[t] += v;
        __syncthreads();
    }
    int totR = a[NB - 1];
    cr[t] = (float)a[t] / fmaxf((float)totR, 1e-6f);
    float v = (float)cumS / fmaxf((float)totS, 1e-6f);
    __syncthreads();

    int cnt = 0;
    for (int j = 0; j < NB; j++) cnt += (cr[j] < v) ? 1 : 0;   // searchsorted left
    table[(size_t)idx * NB + t] = (uint8_t)min(cnt, 255);
}

// ---- Pass D: final composite ----
__global__ void __launch_bounds__(256) compose_kernel(
    const float* __restrict__ src, const float* __restrict__ tgt,
    const float* __restrict__ ms, const uint8_t* __restrict__ mse,
    const uint8_t* __restrict__ mbs, const uint8_t* __restrict__ table,
    float* __restrict__ out, int blocksPer)
{
    int b   = blockIdx.x / blocksPer;
    int blk = blockIdx.x % blocksPer;
    __shared__ uint8_t tb[12 * NB];
    const uint8_t* gt = table + (size_t)b * 12 * NB;
    for (int i = threadIdx.x; i < 12 * NB; i += blockDim.x) tb[i] = gt[i];
    __syncthreads();

    const float* s0 = src + (size_t)b * 3 * HW;
    const float* r0 = tgt + (size_t)b * 3 * HW;
    const float* mk = ms + (size_t)b * 5 * HW;
    const uint8_t* me = mse + (size_t)b * HW;   // src side
    const uint8_t* qb = mbs + (size_t)b * HW;
    float* o = out + (size_t)b * 3 * HW;

    int stride = blocksPer * blockDim.x;
    for (int i = blk * blockDim.x + threadIdx.x; i < HW; i += stride) {
        float x0 = s0[i], x1 = s0[HW + i], x2 = s0[2 * HW + i];
        float d0 = denorm255(x0), d1 = denorm255(x1), d2 = denorm255(x2);
        float m0 = mk[i], m1 = mk[HW + i], m4 = mk[4 * HW + i];
        int mei = me[i];
        int q   = qb[i];
        float p0 = x0, p1 = x1, p2 = x2;
        // skin (region 0)
        if (m1 > 0.0f) {
            float e0 = renorm_lut(tb[(0 * 3 + 0) * NB + min((int)(d0 * m1), 255)]);
            float e1 = renorm_lut(tb[(0 * 3 + 1) * NB + min((int)(d1 * m1), 255)]);
            float e2 = renorm_lut(tb[(0 * 3 + 2) * NB + min((int)(d2 * m1), 255)]);
            p0 = (1.0f - m1) * p0 + m1 * e0;
            p1 = (1.0f - m1) * p1 + m1 * e1;
            p2 = (1.0f - m1) * p2 + m1 * e2;
        }
        // ch4 (region 1)
        if (m4 > 0.0f) {
            float e0 = renorm_lut(tb[(1 * 3 + 0) * NB + min((int)(d0 * m4), 255)]);
            float e1 = renorm_lut(tb[(1 * 3 + 1) * NB + min((int)(d1 * m4), 255)]);
            float e2 = renorm_lut(tb[(1 * 3 + 2) * NB + min((int)(d2 * m4), 255)]);
            p0 = (1.0f - m4) * p0 + m4 * e0;
            p1 = (1.0f - m4) * p1 + m4 * e1;
            p2 = (1.0f - m4) * p2 + m4 * e2;
        }
        // lip (region 2)
        if (m0 > 0.0f) {
            float e0 = renorm_lut(tb[(2 * 3 + 0) * NB + min((int)(d0 * m0), 255)]);
            float e1 = renorm_lut(tb[(2 * 3 + 1) * NB + min((int)(d1 * m0), 255)]);
            float e2 = renorm_lut(tb[(2 * 3 + 2) * NB + min((int)(d2 * m0), 255)]);
            p0 = (1.0f - m0) * p0 + m0 * e0;
            p1 = (1.0f - m0) * p1 + m0 * e1;
            p2 = (1.0f - m0) * p2 + m0 * e2;
        }
        // eye blur blend (region 3): mb = (boxsum/25)*m_se ; zero iff m_se==0
        if (mei > 0) {
            float fm = (float)mei;
            float mb = ((float)q / 25.0f) * fm;
            float e0 = renorm_lut(tb[(3 * 3 + 0) * NB + min((int)(d0 * fm), 255)]);
            float e1 = renorm_lut(tb[(3 * 3 + 1) * NB + min((int)(d1 * fm), 255)]);
            float e2 = renorm_lut(tb[(3 * 3 + 2) * NB + min((int)(d2 * fm), 255)]);
            p0 = (1.0f - mb) * p0 + mb * e0;
            p1 = (1.0f - mb) * p1 + mb * e1;
            p2 = (1.0f - mb) * p2 + mb * e2;
        }
        // alpha composites: (skin,0.3), (m_se,0.8), (lip,0.1)
        float rr0 = r0[i], rr1 = r0[HW + i], rr2 = r0[2 * HW + i];
        float a = 0.3f * m1;
        p0 = (1.0f - a) * p0 + a * rr0;
        p1 = (1.0f - a) * p1 + a * rr1;
        p2 = (1.0f - a) * p2 + a * rr2;
        a = 0.8f * (float)mei;
        p0 = (1.0f - a) * p0 + a * rr0;
        p1 = (1.0f - a) * p1 + a * rr1;
        p2 = (1.0f - a) * p2 + a * rr2;
        a = 0.1f * m0;
        p0 = (1.0f - a) * p0 + a * rr0;
        p1 = (1.0f - a) * p1 + a * rr1;
        p2 = (1.0f - a) * p2 + a * rr2;

        o[i] = p0; o[HW + i] = p1; o[2 * HW + i] = p2;
    }
}

extern "C" void kernel_launch(void* const* d_in, const int* in_sizes, int n_in,
                              void* d_out, int out_size, void* d_ws, size_t ws_size,
                              hipStream_t stream) {
    const float* src = (const float*)d_in[0];   // (16,3,512,512)
    const float* tgt = (const float*)d_in[1];   // (16,3,512,512)
    const float* ms  = (const float*)d_in[2];   // (16,5,512,512)
    const float* mr  = (const float*)d_in[3];   // (16,5,512,512)
    float* out = (float*)d_out;                 // (16,3,512,512)

    // ws layout
    uint8_t* ws = (uint8_t*)d_ws;
    size_t off = 0;
    uint8_t* mse = ws + off; off += (size_t)2 * BB * HW;   // [side][b][HW], values 0/1/2
    uint8_t* tmp = ws + off; off += (size_t)2 * BB * HW;   // scratch
    uint8_t* mbs = ws + off; off += (size_t)BB * HW;       // 5x5 boxsum of m_se (src)
    off = (off + 255) & ~(size_t)255;
    int* hist = (int*)(ws + off); off += (size_t)2 * BB * 12 * NB * sizeof(int);
    uint8_t* table = ws + off; off += (size_t)BB * 12 * NB;

    hipMemsetAsync(hist, 0, (size_t)2 * BB * 12 * NB * sizeof(int), stream);

    rowmax_kernel<<<2 * BB * HH, 256, 0, stream>>>(ms, mr, tmp);
    colmax_kernel<<<2 * BB * HH, 256, 0, stream>>>(ms, mr, tmp, mse);
    rowsum_kernel<<<BB * HH, 256, 0, stream>>>(mse /* src side */, tmp);
    colsum_kernel<<<BB * HH, 256, 0, stream>>>(tmp, mbs);

    const int HB = 32;   // blocks per (batch, side)
    hist_kernel<<<HB * BB * 2, 256, 0, stream>>>(src, tgt, ms, mr, mse, hist, HB);

    table_kernel<<<BB * 4 * 3, NB, 0, stream>>>(hist, table);

    const int CB = 64;   // blocks per batch
    compose_kernel<<<CB * BB, 256, 0, stream>>>(src, tgt, ms, mse, mbs, table, out, CB);
}

// Round 2
// 343.123 us; speedup vs baseline: 1.4195x; 1.4195x over previous
//
#include <hip/hip_runtime.h>
#include <stdint.h>

#define BB 16
#define HH 512
#define WW 512
#define HW (HH*WW)
#define NB 256

// C plane byte layout (one byte per pixel, [side*BB+b][HW]):
//   bits 0-1: e = mask[2]+mask[3]  (0,1,2)   -- dead after hor_kernel
//   bit  2  : mask[0] > 0   (lip)
//   bit  3  : mask[1] > 0   (skin)
//   bit  4  : mask[4] > 0
//   bits 5-6: m_se (0,1,2)  -- written by ver_kernel

__device__ __forceinline__ float denorm255(float x) {
    return fminf(fmaxf((x + 1.0f) * 0.5f, 0.0f), 1.0f) * 255.0f;
}
__device__ __forceinline__ float renorm_lut(int t) {
    return ((float)t / 255.0f) * 2.0f - 1.0f;
}
// byte-granular funnel shift: result byte j = byte (j+r) of (hi:lo), r in 0..3
__device__ __forceinline__ uint32_t alignb(uint32_t hi, uint32_t lo, int r) {
    return (uint32_t)(((((uint64_t)hi) << 32) | lo) >> (8 * r));
}

// ---- K1: fused mask prep: read 5 float planes (both sides), write packed byte plane ----
__global__ void __launch_bounds__(256) prep_kernel(
    const float* __restrict__ ms, const float* __restrict__ mr,
    uint32_t* __restrict__ C)
{
    int t = blockIdx.x * 256 + threadIdx.x;          // u32 chunk (4 px)
    const int perSide = BB * (HW / 4);
    int side = t / perSide;
    int rem  = t - side * perSide;
    int b    = rem / (HW / 4);
    int c    = rem - b * (HW / 4);
    const float* base = (side == 0 ? ms : mr) + (size_t)b * 5 * HW;
    float4 m0 = ((const float4*)(base + 0 * (size_t)HW))[c];
    float4 m1 = ((const float4*)(base + 1 * (size_t)HW))[c];
    float4 m2 = ((const float4*)(base + 2 * (size_t)HW))[c];
    float4 m3 = ((const float4*)(base + 3 * (size_t)HW))[c];
    float4 m4 = ((const float4*)(base + 4 * (size_t)HW))[c];
    float a0[4] = {m0.x, m0.y, m0.z, m0.w};
    float a1[4] = {m1.x, m1.y, m1.z, m1.w};
    float a2[4] = {m2.x, m2.y, m2.z, m2.w};
    float a3[4] = {m3.x, m3.y, m3.z, m3.w};
    float a4[4] = {m4.x, m4.y, m4.z, m4.w};
    uint32_t w = 0;
    #pragma unroll
    for (int j = 0; j < 4; j++) {
        uint32_t e  = (uint32_t)(a2[j] + a3[j]);              // exact 0/1/2
        uint32_t pb = (a0[j] > 0.f ? 4u : 0u) | (a1[j] > 0.f ? 8u : 0u)
                    | (a4[j] > 0.f ? 16u : 0u);
        w |= (e | pb) << (8 * j);
    }
    C[t] = w;
}

// ---- K2: horizontal OR over +-12 px on packed bytes ----
__global__ void __launch_bounds__(256) hor_kernel(
    const uint32_t* __restrict__ C, uint32_t* __restrict__ eh)
{
    int t   = blockIdx.x * 256 + threadIdx.x;        // output word id
    int row = t >> 7;                                // 128 words per image row
    int w   = t & 127;
    const uint32_t* rp = C + (size_t)row * 128;
    uint32_t arr[7];
    #pragma unroll
    for (int k = 0; k < 7; k++) {
        int idx = w + k - 3;
        arr[k] = (idx >= 0 && idx < 128) ? (rp[idx] & 0x03030303u) : 0u;
    }
    uint32_t acc = arr[3];
    #pragma unroll
    for (int s = 1; s <= 12; s++) {
        int a = s >> 2, r = s & 3;
        uint32_t vp, vm;
        if (r == 0) {
            vp = arr[3 + a];
            vm = arr[3 - a];
        } else {
            vp = alignb(arr[3 + a + 1], arr[3 + a], r);
            int am = (s + 3) >> 2;
            vm = alignb(arr[3 - am + 1], arr[3 - am], 4 - r);
        }
        acc |= vp | vm;
    }
    eh[t] = acc;
}

// ---- K3: vertical OR over +-12 rows, map 3->2, AND with m1, pack into C bits 5-6 ----
__global__ void __launch_bounds__(256) ver_kernel(
    const uint32_t* __restrict__ eh, uint32_t* __restrict__ C)
{
    int t   = blockIdx.x * 256 + threadIdx.x;
    int sb  = t >> 12;            // 128 ygroups * 32 chunks per plane
    int rem = t & 4095;
    int yg  = rem >> 5;
    int ck  = rem & 31;
    int y0  = yg << 2;
    const uint4* P = (const uint4*)(eh + (size_t)sb * (HW / 4));
    auto R = [&](int y) -> uint4 {
        uint4 z = {0, 0, 0, 0};
        if (y < 0 || y >= HH) return z;
        return P[y * 32 + ck];
    };
    uint4 core = {0, 0, 0, 0};
    #pragma unroll
    for (int yy = -9; yy <= 12; yy++) {
        uint4 r = R(y0 + yy);
        core.x |= r.x; core.y |= r.y; core.z |= r.z; core.w |= r.w;
    }
    uint4 b0 = R(y0 - 12), b1 = R(y0 - 11), b2 = R(y0 - 10);
    uint4 a0 = R(y0 + 13), a1 = R(y0 + 14), a2 = R(y0 + 15);

    uint4* C4 = (uint4*)(C + (size_t)sb * (HW / 4));
    #pragma unroll
    for (int i = 0; i < 4; i++) {
        uint4 v = core;
        if (i == 0) { v.x|=b0.x|b1.x|b2.x; v.y|=b0.y|b1.y|b2.y; v.z|=b0.z|b1.z|b2.z; v.w|=b0.w|b1.w|b2.w; }
        if (i == 1) { v.x|=b1.x|b2.x|a0.x; v.y|=b1.y|b2.y|a0.y; v.z|=b1.z|b2.z|a0.z; v.w|=b1.w|b2.w|a0.w; }
        if (i == 2) { v.x|=b2.x|a0.x|a1.x; v.y|=b2.y|a0.y|a1.y; v.z|=b2.z|a0.z|a1.z; v.w|=b2.w|a0.w|a1.w; }
        if (i == 3) { v.x|=a0.x|a1.x|a2.x; v.y|=a0.y|a1.y|a2.y; v.z|=a0.z|a1.z|a2.z; v.w|=a0.w|a1.w|a2.w; }
        int idx = (y0 + i) * 32 + ck;
        uint4 cw = C4[idx];
        #pragma unroll
        for (int q = 0; q < 4; q++) {
            uint32_t vv = (&v.x)[q];
            uint32_t cc = (&cw.x)[q];
            uint32_t t3 = vv & (vv >> 1) & 0x01010101u;   // byte==3 detector
            vv -= t3;                                      // map 3 -> 2
            uint32_t m1b = (cc >> 3) & 0x01010101u;        // skin mask bits
            vv &= m1b * 255u;                              // select where m1
            (&cw.x)[q] = cc | (vv << 5);
        }
        C4[idx] = cw;
    }
}

// ---- K4: fused 5x5 box sum of m_se (src side), packed byte adds (sum<=50) ----
__global__ void __launch_bounds__(256) blur_kernel(
    const uint32_t* __restrict__ C, uint32_t* __restrict__ mbs)
{
    int t   = blockIdx.x * 256 + threadIdx.x;   // word id, src side only
    int b   = t >> 14;                          // HW/4 = 16384*4... 65536/4? (HW/4=65536 words): t>>16? no:
    // HW/4 = 65536 words per image -> b = t / 65536
    b = t >> 16;
    int rem = t & 65535;
    int y   = rem >> 7;
    int w   = rem & 127;
    const uint32_t* P = C + (size_t)b * (HW / 4);   // side 0
    uint32_t vm1 = 0, v0 = 0, vp1 = 0;
    #pragma unroll
    for (int dy = -2; dy <= 2; dy++) {
        int yy = y + dy;
        if (yy < 0 || yy >= HH) continue;
        const uint32_t* rp = P + yy * 128;
        if (w > 0)   vm1 += (rp[w - 1] >> 5) & 0x03030303u;
        v0 += (rp[w] >> 5) & 0x03030303u;
        if (w < 127) vp1 += (rp[w + 1] >> 5) & 0x03030303u;
    }
    uint32_t s = v0;
    s += alignb(v0, vm1, 2);
    s += alignb(v0, vm1, 3);
    s += alignb(vp1, v0, 1);
    s += alignb(vp1, v0, 2);
    mbs[t] = s;
}

// ---- K5: 12 weighted histograms per (batch, side), vectorized loads ----
#define HB 64
__global__ void __launch_bounds__(256) hist_kernel(
    const float* __restrict__ src, const float* __restrict__ tgt,
    const uint32_t* __restrict__ C, int* __restrict__ hist)
{
    int bs  = blockIdx.x / HB;
    int blk = blockIdx.x % HB;
    int b = bs >> 1, side = bs & 1;
    const float* img = (side ? tgt : src) + (size_t)b * 3 * HW;
    const float4* i0 = (const float4*)(img);
    const float4* i1 = (const float4*)(img + HW);
    const float4* i2 = (const float4*)(img + 2 * (size_t)HW);
    const uint32_t* pc = C + (size_t)(side * BB + b) * (HW / 4);

    __shared__ int h[12 * NB];
    for (int i = threadIdx.x; i < 12 * NB; i += 256) h[i] = 0;
    __syncthreads();

    for (int c = blk * 256 + threadIdx.x; c < HW / 4; c += HB * 256) {
        float4 v0 = i0[c], v1 = i1[c], v2 = i2[c];
        uint32_t cw = pc[c];
        float d0[4] = {denorm255(v0.x), denorm255(v0.y), denorm255(v0.z), denorm255(v0.w)};
        float d1[4] = {denorm255(v1.x), denorm255(v1.y), denorm255(v1.z), denorm255(v1.w)};
        float d2[4] = {denorm255(v2.x), denorm255(v2.y), denorm255(v2.z), denorm255(v2.w)};
        #pragma unroll
        for (int j = 0; j < 4; j++) {
            uint32_t pb = (cw >> (8 * j)) & 0xFFu;
            if (pb & 8u) {   // skin (region 0)
                atomicAdd(&h[0 * NB + min((int)d0[j], 255)], 1);
                atomicAdd(&h[1 * NB + min((int)d1[j], 255)], 1);
                atomicAdd(&h[2 * NB + min((int)d2[j], 255)], 1);
            }
            if (pb & 16u) {  // ch4 (region 1)
                atomicAdd(&h[3 * NB + min((int)d0[j], 255)], 1);
                atomicAdd(&h[4 * NB + min((int)d1[j], 255)], 1);
                atomicAdd(&h[5 * NB + min((int)d2[j], 255)], 1);
            }
            if (pb & 4u) {   // lip (region 2)
                atomicAdd(&h[6 * NB + min((int)d0[j], 255)], 1);
                atomicAdd(&h[7 * NB + min((int)d1[j], 255)], 1);
                atomicAdd(&h[8 * NB + min((int)d2[j], 255)], 1);
            }
            int mei = (int)((pb >> 5) & 3u);   // eye (region 3), weight 1/2
            if (mei) {
                float fm = (float)mei;
                atomicAdd(&h[ 9 * NB + min((int)(d0[j] * fm), 255)], mei);
                atomicAdd(&h[10 * NB + min((int)(d1[j] * fm), 255)], mei);
                atomicAdd(&h[11 * NB + min((int)(d2[j] * fm), 255)], mei);
            }
        }
    }
    __syncthreads();
    int* gh = hist + (size_t)bs * 12 * NB;
    for (int i = threadIdx.x; i < 12 * NB; i += 256)
        if (h[i]) atomicAdd(&gh[i], h[i]);
}

// ---- K6: cdf + searchsorted -> 256-entry LUT per (b, region, channel) ----
__global__ void __launch_bounds__(NB) table_kernel(
    const int* __restrict__ hist, uint8_t* __restrict__ table)
{
    int idx = blockIdx.x;               // (b*4+rg)*3+c, 192 blocks
    int c = idx % 3; int rest = idx / 3; int rg = rest & 3; int b = rest >> 2;
    const int* hs = hist + ((size_t)((b * 2 + 0) * 4 + rg) * 3 + c) * NB;
    const int* hr = hist + ((size_t)((b * 2 + 1) * 4 + rg) * 3 + c) * NB;
    __shared__ int a[NB];
    __shared__ float cr[NB];
    int t = threadIdx.x;

    a[t] = hs[t];
    __syncthreads();
    for (int off = 1; off < NB; off <<= 1) {
        int v = (t >= off) ? a[t - off] : 0;
        __syncthreads();
        a[t] += v;
        __syncthreads();
    }
    int totS = a[NB - 1];
    int cumS = a[t];
    __syncthreads();

    a[t] = hr[t];
    __syncthreads();
    for (int off = 1; off < NB; off <<= 1) {
        int v = (t >= off) ? a[t - off] : 0;
        __syncthreads();
        a[t] += v;
        __syncthreads();
    }
    int totR = a[NB - 1];
    cr[t] = (float)a[t] / fmaxf((float)totR, 1e-6f);
    float v = (float)cumS / fmaxf((float)totS, 1e-6f);
    __syncthreads();

    int cnt = 0;
    for (int j = 0; j < NB; j++) cnt += (cr[j] < v) ? 1 : 0;
    table[(size_t)idx * NB + t] = (uint8_t)min(cnt, 255);
}

// ---- K7: final composite, branchless, vectorized ----
#define CB 64
__global__ void __launch_bounds__(256) compose_kernel(
    const float* __restrict__ src, const float* __restrict__ tgt,
    const uint32_t* __restrict__ C, const uint32_t* __restrict__ mbs,
    const uint8_t* __restrict__ table, float* __restrict__ out)
{
    int b   = blockIdx.x / CB;
    int blk = blockIdx.x % CB;
    __shared__ uint8_t tb[12 * NB];
    const uint8_t* gt = table + (size_t)b * 12 * NB;
    for (int i = threadIdx.x; i < 12 * NB; i += 256) tb[i] = gt[i];
    __syncthreads();

    const float4* s0 = (const float4*)(src + (size_t)b * 3 * HW);
    const float4* s1 = s0 + HW / 4;
    const float4* s2 = s1 + HW / 4;
    const float4* t0 = (const float4*)(tgt + (size_t)b * 3 * HW);
    const float4* t1 = t0 + HW / 4;
    const float4* t2 = t1 + HW / 4;
    const uint32_t* pc = C + (size_t)b * (HW / 4);       // src side
    const uint32_t* qc = mbs + (size_t)b * (HW / 4);
    float4* o0 = (float4*)(out + (size_t)b * 3 * HW);
    float4* o1 = o0 + HW / 4;
    float4* o2 = o1 + HW / 4;

    for (int c = blk * 256 + threadIdx.x; c < HW / 4; c += CB * 256) {
        float4 x0 = s0[c], x1 = s1[c], x2 = s2[c];
        float4 r0 = t0[c], r1 = t1[c], r2 = t2[c];
        uint32_t cw = pc[c];
        uint32_t qw = qc[c];
        float X0[4] = {x0.x, x0.y, x0.z, x0.w};
        float X1[4] = {x1.x, x1.y, x1.z, x1.w};
        float X2[4] = {x2.x, x2.y, x2.z, x2.w};
        float R0[4] = {r0.x, r0.y, r0.z, r0.w};
        float R1[4] = {r1.x, r1.y, r1.z, r1.w};
        float R2[4] = {r2.x, r2.y, r2.z, r2.w};
        float O0[4], O1[4], O2[4];
        #pragma unroll
        for (int j = 0; j < 4; j++) {
            uint32_t pb = (cw >> (8 * j)) & 0xFFu;
            float q = (float)((qw >> (8 * j)) & 0xFFu);
            float m0f = (float)((pb >> 2) & 1u);
            float m1f = (float)((pb >> 3) & 1u);
            float m4f = (float)((pb >> 4) & 1u);
            float fm  = (float)((pb >> 5) & 3u);
            float d0 = denorm255(X0[j]), d1 = denorm255(X1[j]), d2 = denorm255(X2[j]);
            float p0 = X0[j], p1 = X1[j], p2 = X2[j];
            // skin
            {
                float e0 = renorm_lut(tb[0 * NB + min((int)(d0 * m1f), 255)]);
                float e1 = renorm_lut(tb[1 * NB + min((int)(d1 * m1f), 255)]);
                float e2 = renorm_lut(tb[2 * NB + min((int)(d2 * m1f), 255)]);
                p0 = (1.0f - m1f) * p0 + m1f * e0;
                p1 = (1.0f - m1f) * p1 + m1f * e1;
                p2 = (1.0f - m1f) * p2 + m1f * e2;
            }
            // ch4
            {
                float e0 = renorm_lut(tb[3 * NB + min((int)(d0 * m4f), 255)]);
                float e1 = renorm_lut(tb[4 * NB + min((int)(d1 * m4f), 255)]);
                float e2 = renorm_lut(tb[5 * NB + min((int)(d2 * m4f), 255)]);
                p0 = (1.0f - m4f) * p0 + m4f * e0;
                p1 = (1.0f - m4f) * p1 + m4f * e1;
                p2 = (1.0f - m4f) * p2 + m4f * e2;
            }
            // lip
            {
                float e0 = renorm_lut(tb[6 * NB + min((int)(d0 * m0f), 255)]);
                float e1 = renorm_lut(tb[7 * NB + min((int)(d1 * m0f), 255)]);
                float e2 = renorm_lut(tb[8 * NB + min((int)(d2 * m0f), 255)]);
                p0 = (1.0f - m0f) * p0 + m0f * e0;
                p1 = (1.0f - m0f) * p1 + m0f * e1;
                p2 = (1.0f - m0f) * p2 + m0f * e2;
            }
            // eye blur blend: mb = (boxsum/25)*m_se
            {
                float mb = (q * (1.0f / 25.0f)) * fm;
                float e0 = renorm_lut(tb[ 9 * NB + min((int)(d0 * fm), 255)]);
                float e1 = renorm_lut(tb[10 * NB + min((int)(d1 * fm), 255)]);
                float e2 = renorm_lut(tb[11 * NB + min((int)(d2 * fm), 255)]);
                p0 = (1.0f - mb) * p0 + mb * e0;
                p1 = (1.0f - mb) * p1 + mb * e1;
                p2 = (1.0f - mb) * p2 + mb * e2;
            }
            // alpha composites
            float a = 0.3f * m1f;
            p0 = (1.0f - a) * p0 + a * R0[j];
            p1 = (1.0f - a) * p1 + a * R1[j];
            p2 = (1.0f - a) * p2 + a * R2[j];
            a = 0.8f * fm;
            p0 = (1.0f - a) * p0 + a * R0[j];
            p1 = (1.0f - a) * p1 + a * R1[j];
            p2 = (1.0f - a) * p2 + a * R2[j];
            a = 0.1f * m0f;
            p0 = (1.0f - a) * p0 + a * R0[j];
            p1 = (1.0f - a) * p1 + a * R1[j];
            p2 = (1.0f - a) * p2 + a * R2[j];
            O0[j] = p0; O1[j] = p1; O2[j] = p2;
        }
        float4 w0 = {O0[0], O0[1], O0[2], O0[3]};
        float4 w1 = {O1[0], O1[1], O1[2], O1[3]};
        float4 w2 = {O2[0], O2[1], O2[2], O2[3]};
        o0[c] = w0; o1[c] = w1; o2[c] = w2;
    }
}

extern "C" void kernel_launch(void* const* d_in, const int* in_sizes, int n_in,
                              void* d_out, int out_size, void* d_ws, size_t ws_size,
                              hipStream_t stream) {
    const float* src = (const float*)d_in[0];   // (16,3,512,512)
    const float* tgt = (const float*)d_in[1];
    const float* ms  = (const float*)d_in[2];   // (16,5,512,512)
    const float* mr  = (const float*)d_in[3];
    float* out = (float*)d_out;

    uint8_t* ws = (uint8_t*)d_ws;
    uint32_t* C   = (uint32_t*)(ws);                                   // 2*BB*HW bytes
    uint32_t* eh  = (uint32_t*)(ws + (size_t)2 * BB * HW);             // 2*BB*HW bytes
    uint32_t* mbs = (uint32_t*)(ws + (size_t)4 * BB * HW);             // BB*HW bytes
    int* hist     = (int*)(ws + (size_t)5 * BB * HW);                  // 2*BB*12*NB*4
    uint8_t* table = ws + (size_t)5 * BB * HW + (size_t)2 * BB * 12 * NB * 4;

    hipMemsetAsync(hist, 0, (size_t)2 * BB * 12 * NB * sizeof(int), stream);

    prep_kernel<<<2 * BB * HW / 4 / 256, 256, 0, stream>>>(ms, mr, C);
    hor_kernel<<<2 * BB * HW / 4 / 256, 256, 0, stream>>>(C, eh);
    ver_kernel<<<2 * BB * (HH / 4) * (WW / 16) / 256, 256, 0, stream>>>(eh, C);
    blur_kernel<<<BB * HW / 4 / 256, 256, 0, stream>>>(C, mbs);
    hist_kernel<<<2 * BB * HB, 256, 0, stream>>>(src, tgt, C, hist);
    table_kernel<<<BB * 4 * 3, NB, 0, stream>>>(hist, table);
    compose_kernel<<<BB * CB, 256, 0, stream>>>(src, tgt, C, mbs, table, out);
}

// Round 3
// 333.739 us; speedup vs baseline: 1.4594x; 1.0281x over previous
//
#include <hip/hip_runtime.h>
#include <stdint.h>

#define BB 16
#define HH 512
#define WW 512
#define HW (HH*WW)
#define NB 256

// C plane byte layout (one byte per pixel, [side*BB+b][HW]):
//   bits 0-1: e = mask[2]+mask[3]  (0,1,2)
//   bit  2  : mask[0] > 0   (lip)
//   bit  3  : mask[1] > 0   (skin)
//   bit  4  : mask[4] > 0
//   bits 5-6: m_se (0,1,2)  -- merged in by ver_kernel

__device__ __forceinline__ float denorm255(float x) {
    return fminf(fmaxf((x + 1.0f) * 0.5f, 0.0f), 1.0f) * 255.0f;
}
__device__ __forceinline__ float renorm_lut(int t) {
    return ((float)t / 255.0f) * 2.0f - 1.0f;
}
// byte-granular funnel shift: result byte j = byte (j+r) of (hi:lo), r in 0..3
__device__ __forceinline__ uint32_t alignb(uint32_t hi, uint32_t lo, int r) {
    return (uint32_t)(((((uint64_t)hi) << 32) | lo) >> (8 * r));
}

// ---- K1: fused prep + horizontal +-12 OR. Block = 8 full rows of one plane. ----
// 256 threads: thread (r=t>>5, c=t&31) produces uint4 (16 px) at row r, word-col c.
__global__ void __launch_bounds__(256) prep_hor_kernel(
    const float* __restrict__ ms, const float* __restrict__ mr,
    uint4* __restrict__ C, uint4* __restrict__ eh)
{
    int blk  = blockIdx.x;                 // 0 .. 2*BB*64-1
    int side = blk >> 10;                  // BB*64 = 1024
    int rem  = blk & 1023;
    int b    = rem >> 6;
    int rg   = rem & 63;
    int r    = threadIdx.x >> 5;
    int c    = threadIdx.x & 31;
    int y    = (rg << 3) + r;

    const float* base = (side ? mr : ms) + (size_t)b * 5 * HW + (size_t)y * WW + c * 16;

    float4 v[5][4];
    #pragma unroll
    for (int p = 0; p < 5; p++) {
        const float4* pp = (const float4*)(base + (size_t)p * HW);
        #pragma unroll
        for (int q = 0; q < 4; q++) v[p][q] = pp[q];
    }
    uint4 cw, ew;
    #pragma unroll
    for (int w = 0; w < 4; w++) {
        uint32_t wc = 0;
        #pragma unroll
        for (int j = 0; j < 4; j++) {
            float a0 = (&v[0][w].x)[j];
            float a1 = (&v[1][w].x)[j];
            float a2 = (&v[2][w].x)[j];
            float a3 = (&v[3][w].x)[j];
            float a4 = (&v[4][w].x)[j];
            uint32_t e  = (uint32_t)(a2 + a3);              // exact 0/1/2
            uint32_t pb = (a0 > 0.f ? 4u : 0u) | (a1 > 0.f ? 8u : 0u)
                        | (a4 > 0.f ? 16u : 0u);
            wc |= (e | pb) << (8 * j);
        }
        (&cw.x)[w] = wc;
        (&ew.x)[w] = wc & 0x03030303u;
    }
    size_t plane = (size_t)(side * BB + b);
    int widx = y * 32 + c;                 // uint4 index within plane
    C[plane * (HW / 16) + widx] = cw;

    __shared__ uint4 se[8][32];
    se[r][c] = ew;
    __syncthreads();

    const uint4 zero4 = {0u, 0u, 0u, 0u};
    uint4 L = (c > 0)  ? se[r][c - 1] : zero4;
    uint4 M = se[r][c];
    uint4 R = (c < 31) ? se[r][c + 1] : zero4;
    uint32_t W[12] = {L.x, L.y, L.z, L.w, M.x, M.y, M.z, M.w, R.x, R.y, R.z, R.w};

    uint4 outw;
    #pragma unroll
    for (int k = 0; k < 4; k++) {
        uint32_t arr[7];
        #pragma unroll
        for (int i = 0; i < 7; i++) arr[i] = W[k + 1 + i];
        uint32_t acc = arr[3];
        #pragma unroll
        for (int s = 1; s <= 12; s++) {
            int a = s >> 2, rr = s & 3;
            uint32_t vp, vm;
            if (rr == 0) {
                vp = arr[3 + a];
                vm = arr[3 - a];
            } else {
                vp = alignb(arr[3 + a + 1], arr[3 + a], rr);
                int am = (s + 3) >> 2;
                vm = alignb(arr[3 - am + 1], arr[3 - am], 4 - rr);
            }
            acc |= vp | vm;
        }
        (&outw.x)[k] = acc;
    }
    eh[plane * (HW / 16) + widx] = outw;
}

// ---- K2: vertical OR over +-12 rows, map 3->2, AND with m1, pack into C bits 5-6 ----
__global__ void __launch_bounds__(256) ver_kernel(
    const uint32_t* __restrict__ eh, uint32_t* __restrict__ C)
{
    int t   = blockIdx.x * 256 + threadIdx.x;
    int sb  = t >> 12;            // 128 ygroups * 32 chunks per plane
    int rem = t & 4095;
    int yg  = rem >> 5;
    int ck  = rem & 31;
    int y0  = yg << 2;
    const uint4* P = (const uint4*)(eh + (size_t)sb * (HW / 4));
    auto R = [&](int y) -> uint4 {
        uint4 z = {0, 0, 0, 0};
        if (y < 0 || y >= HH) return z;
        return P[y * 32 + ck];
    };
    uint4 core = {0, 0, 0, 0};
    #pragma unroll
    for (int yy = -9; yy <= 12; yy++) {
        uint4 r = R(y0 + yy);
        core.x |= r.x; core.y |= r.y; core.z |= r.z; core.w |= r.w;
    }
    uint4 b0 = R(y0 - 12), b1 = R(y0 - 11), b2 = R(y0 - 10);
    uint4 a0 = R(y0 + 13), a1 = R(y0 + 14), a2 = R(y0 + 15);

    uint4* C4 = (uint4*)(C + (size_t)sb * (HW / 4));
    #pragma unroll
    for (int i = 0; i < 4; i++) {
        uint4 v = core;
        if (i == 0) { v.x|=b0.x|b1.x|b2.x; v.y|=b0.y|b1.y|b2.y; v.z|=b0.z|b1.z|b2.z; v.w|=b0.w|b1.w|b2.w; }
        if (i == 1) { v.x|=b1.x|b2.x|a0.x; v.y|=b1.y|b2.y|a0.y; v.z|=b1.z|b2.z|a0.z; v.w|=b1.w|b2.w|a0.w; }
        if (i == 2) { v.x|=b2.x|a0.x|a1.x; v.y|=b2.y|a0.y|a1.y; v.z|=b2.z|a0.z|a1.z; v.w|=b2.w|a0.w|a1.w; }
        if (i == 3) { v.x|=a0.x|a1.x|a2.x; v.y|=a0.y|a1.y|a2.y; v.z|=a0.z|a1.z|a2.z; v.w|=a0.w|a1.w|a2.w; }
        int idx = (y0 + i) * 32 + ck;
        uint4 cw = C4[idx];
        #pragma unroll
        for (int q = 0; q < 4; q++) {
            uint32_t vv = (&v.x)[q];
            uint32_t cc = (&cw.x)[q];
            uint32_t t3 = vv & (vv >> 1) & 0x01010101u;   // byte==3 detector
            vv -= t3;                                      // map 3 -> 2
            uint32_t m1b = (cc >> 3) & 0x01010101u;        // skin mask bits
            vv &= m1b * 255u;                              // select where m1
            (&cw.x)[q] = cc | (vv << 5);
        }
        C4[idx] = cw;
    }
}

// ---- K3: 5x5 box sum of m_se (src side), 16 px per thread ----
__global__ void __launch_bounds__(256) blur_kernel(
    const uint32_t* __restrict__ C, uint4* __restrict__ mbs)
{
    int t = blockIdx.x * 256 + threadIdx.x;   // 16*16384 uint4 / 256 = 1024 blocks
    int b = t >> 14;
    int rem = t & 16383;
    int y = rem >> 5;
    int c = rem & 31;
    const uint32_t* P = C + (size_t)b * (HW / 4);   // src side plane
    int c4 = c << 2;
    uint32_t s[6] = {0u, 0u, 0u, 0u, 0u, 0u};
    #pragma unroll
    for (int dy = -2; dy <= 2; dy++) {
        int yy = y + dy;
        if (yy < 0 || yy >= HH) continue;
        const uint32_t* rp = P + yy * 128;
        uint32_t l = (c > 0)  ? rp[c4 - 1] : 0u;
        uint4 m = *((const uint4*)(rp + c4));
        uint32_t rr = (c < 31) ? rp[c4 + 4] : 0u;
        s[0] += (l   >> 5) & 0x03030303u;
        s[1] += (m.x >> 5) & 0x03030303u;
        s[2] += (m.y >> 5) & 0x03030303u;
        s[3] += (m.z >> 5) & 0x03030303u;
        s[4] += (m.w >> 5) & 0x03030303u;
        s[5] += (rr  >> 5) & 0x03030303u;
    }
    uint4 o;
    #pragma unroll
    for (int k = 0; k < 4; k++) {
        uint32_t v = s[k + 1];
        v += alignb(s[k + 1], s[k],     2);
        v += alignb(s[k + 1], s[k],     3);
        v += alignb(s[k + 2], s[k + 1], 1);
        v += alignb(s[k + 2], s[k + 1], 2);
        (&o.x)[k] = v;
    }
    mbs[t] = o;
}

// ---- K4: 12 weighted histograms per (batch, side), 8 px per iteration ----
#define HB 32
__device__ __forceinline__ void hist4(int* h, uint32_t cw,
                                      float4 v0, float4 v1, float4 v2)
{
    float d0[4] = {denorm255(v0.x), denorm255(v0.y), denorm255(v0.z), denorm255(v0.w)};
    float d1[4] = {denorm255(v1.x), denorm255(v1.y), denorm255(v1.z), denorm255(v1.w)};
    float d2[4] = {denorm255(v2.x), denorm255(v2.y), denorm255(v2.z), denorm255(v2.w)};
    #pragma unroll
    for (int j = 0; j < 4; j++) {
        uint32_t pb = (cw >> (8 * j)) & 0xFFu;
        if (pb & 8u) {
            atomicAdd(&h[0 * NB + min((int)d0[j], 255)], 1);
            atomicAdd(&h[1 * NB + min((int)d1[j], 255)], 1);
            atomicAdd(&h[2 * NB + min((int)d2[j], 255)], 1);
        }
        if (pb & 16u) {
            atomicAdd(&h[3 * NB + min((int)d0[j], 255)], 1);
            atomicAdd(&h[4 * NB + min((int)d1[j], 255)], 1);
            atomicAdd(&h[5 * NB + min((int)d2[j], 255)], 1);
        }
        if (pb & 4u) {
            atomicAdd(&h[6 * NB + min((int)d0[j], 255)], 1);
            atomicAdd(&h[7 * NB + min((int)d1[j], 255)], 1);
            atomicAdd(&h[8 * NB + min((int)d2[j], 255)], 1);
        }
        int mei = (int)((pb >> 5) & 3u);
        if (mei) {
            float fm = (float)mei;
            atomicAdd(&h[ 9 * NB + min((int)(d0[j] * fm), 255)], mei);
            atomicAdd(&h[10 * NB + min((int)(d1[j] * fm), 255)], mei);
            atomicAdd(&h[11 * NB + min((int)(d2[j] * fm), 255)], mei);
        }
    }
}

__global__ void __launch_bounds__(256) hist_kernel(
    const float* __restrict__ src, const float* __restrict__ tgt,
    const uint32_t* __restrict__ C, int* __restrict__ hist)
{
    int bs  = blockIdx.x / HB;
    int blk = blockIdx.x % HB;
    int b = bs >> 1, side = bs & 1;
    const float* img = (side ? tgt : src) + (size_t)b * 3 * HW;
    const float4* i0 = (const float4*)(img);
    const float4* i1 = (const float4*)(img + HW);
    const float4* i2 = (const float4*)(img + 2 * (size_t)HW);
    const uint2* pc = (const uint2*)(C + (size_t)(side * BB + b) * (HW / 4));

    __shared__ int h[12 * NB];
    for (int i = threadIdx.x; i < 12 * NB; i += 256) h[i] = 0;
    __syncthreads();

    for (int c = blk * 256 + threadIdx.x; c < HW / 8; c += HB * 256) {
        uint2 cw = pc[c];
        float4 a0 = i0[2 * c], b0 = i0[2 * c + 1];
        float4 a1 = i1[2 * c], b1 = i1[2 * c + 1];
        float4 a2 = i2[2 * c], b2 = i2[2 * c + 1];
        hist4(h, cw.x, a0, a1, a2);
        hist4(h, cw.y, b0, b1, b2);
    }
    __syncthreads();
    int* gh = hist + (size_t)bs * 12 * NB;
    for (int i = threadIdx.x; i < 12 * NB; i += 256)
        if (h[i]) atomicAdd(&gh[i], h[i]);
}

// ---- K5: cdf + searchsorted -> 256-entry LUT per (b, region, channel) ----
__global__ void __launch_bounds__(NB) table_kernel(
    const int* __restrict__ hist, uint8_t* __restrict__ table)
{
    int idx = blockIdx.x;               // (b*4+rg)*3+c, 192 blocks
    int c = idx % 3; int rest = idx / 3; int rg = rest & 3; int b = rest >> 2;
    const int* hs = hist + ((size_t)((b * 2 + 0) * 4 + rg) * 3 + c) * NB;
    const int* hr = hist + ((size_t)((b * 2 + 1) * 4 + rg) * 3 + c) * NB;
    __shared__ int a[NB];
    __shared__ float cr[NB];
    int t = threadIdx.x;

    a[t] = hs[t];
    __syncthreads();
    for (int off = 1; off < NB; off <<= 1) {
        int v = (t >= off) ? a[t - off] : 0;
        __syncthreads();
        a[t] += v;
        __syncthreads();
    }
    int totS = a[NB - 1];
    int cumS = a[t];
    __syncthreads();

    a[t] = hr[t];
    __syncthreads();
    for (int off = 1; off < NB; off <<= 1) {
        int v = (t >= off) ? a[t - off] : 0;
        __syncthreads();
        a[t] += v;
        __syncthreads();
    }
    int totR = a[NB - 1];
    cr[t] = (float)a[t] / fmaxf((float)totR, 1e-6f);
    float v = (float)cumS / fmaxf((float)totS, 1e-6f);
    __syncthreads();

    int cnt = 0;
    for (int j = 0; j < NB; j++) cnt += (cr[j] < v) ? 1 : 0;
    table[(size_t)idx * NB + t] = (uint8_t)min(cnt, 255);
}

// ---- K6: final composite, 8 px per thread, single-shot ----
__device__ __forceinline__ void proc4(uint32_t cw, uint32_t qw,
    float4 x0, float4 x1, float4 x2, float4 r0, float4 r1, float4 r2,
    const uint8_t* tb, float4& o0, float4& o1, float4& o2)
{
    float X0[4] = {x0.x, x0.y, x0.z, x0.w};
    float X1[4] = {x1.x, x1.y, x1.z, x1.w};
    float X2[4] = {x2.x, x2.y, x2.z, x2.w};
    float R0[4] = {r0.x, r0.y, r0.z, r0.w};
    float R1[4] = {r1.x, r1.y, r1.z, r1.w};
    float R2[4] = {r2.x, r2.y, r2.z, r2.w};
    #pragma unroll
    for (int j = 0; j < 4; j++) {
        uint32_t pb = (cw >> (8 * j)) & 0xFFu;
        float q = (float)((qw >> (8 * j)) & 0xFFu);
        float m0f = (float)((pb >> 2) & 1u);
        float m1f = (float)((pb >> 3) & 1u);
        float m4f = (float)((pb >> 4) & 1u);
        float fm  = (float)((pb >> 5) & 3u);
        float d0 = denorm255(X0[j]), d1 = denorm255(X1[j]), d2 = denorm255(X2[j]);
        float p0 = X0[j], p1 = X1[j], p2 = X2[j];
        {
            float e0 = renorm_lut(tb[0 * NB + min((int)(d0 * m1f), 255)]);
            float e1 = renorm_lut(tb[1 * NB + min((int)(d1 * m1f), 255)]);
            float e2 = renorm_lut(tb[2 * NB + min((int)(d2 * m1f), 255)]);
            p0 = (1.0f - m1f) * p0 + m1f * e0;
            p1 = (1.0f - m1f) * p1 + m1f * e1;
            p2 = (1.0f - m1f) * p2 + m1f * e2;
        }
        {
            float e0 = renorm_lut(tb[3 * NB + min((int)(d0 * m4f), 255)]);
            float e1 = renorm_lut(tb[4 * NB + min((int)(d1 * m4f), 255)]);
            float e2 = renorm_lut(tb[5 * NB + min((int)(d2 * m4f), 255)]);
            p0 = (1.0f - m4f) * p0 + m4f * e0;
            p1 = (1.0f - m4f) * p1 + m4f * e1;
            p2 = (1.0f - m4f) * p2 + m4f * e2;
        }
        {
            float e0 = renorm_lut(tb[6 * NB + min((int)(d0 * m0f), 255)]);
            float e1 = renorm_lut(tb[7 * NB + min((int)(d1 * m0f), 255)]);
            float e2 = renorm_lut(tb[8 * NB + min((int)(d2 * m0f), 255)]);
            p0 = (1.0f - m0f) * p0 + m0f * e0;
            p1 = (1.0f - m0f) * p1 + m0f * e1;
            p2 = (1.0f - m0f) * p2 + m0f * e2;
        }
        {
            float mb = (q * (1.0f / 25.0f)) * fm;
            float e0 = renorm_lut(tb[ 9 * NB + min((int)(d0 * fm), 255)]);
            float e1 = renorm_lut(tb[10 * NB + min((int)(d1 * fm), 255)]);
            float e2 = renorm_lut(tb[11 * NB + min((int)(d2 * fm), 255)]);
            p0 = (1.0f - mb) * p0 + mb * e0;
            p1 = (1.0f - mb) * p1 + mb * e1;
            p2 = (1.0f - mb) * p2 + mb * e2;
        }
        float a = 0.3f * m1f;
        p0 = (1.0f - a) * p0 + a * R0[j];
        p1 = (1.0f - a) * p1 + a * R1[j];
        p2 = (1.0f - a) * p2 + a * R2[j];
        a = 0.8f * fm;
        p0 = (1.0f - a) * p0 + a * R0[j];
        p1 = (1.0f - a) * p1 + a * R1[j];
        p2 = (1.0f - a) * p2 + a * R2[j];
        a = 0.1f * m0f;
        p0 = (1.0f - a) * p0 + a * R0[j];
        p1 = (1.0f - a) * p1 + a * R1[j];
        p2 = (1.0f - a) * p2 + a * R2[j];
        (&o0.x)[j] = p0; (&o1.x)[j] = p1; (&o2.x)[j] = p2;
    }
}

__global__ void __launch_bounds__(256) compose_kernel(
    const float* __restrict__ src, const float* __restrict__ tgt,
    const uint32_t* __restrict__ C, const uint32_t* __restrict__ mbs,
    const uint8_t* __restrict__ table, float* __restrict__ out)
{
    int t = blockIdx.x * 256 + threadIdx.x;   // 16 * 32768 / 256 = 2048 blocks
    int b = t >> 15;
    int c = t & 32767;                        // uint2 / float4-pair index

    __shared__ uint8_t tb[12 * NB];
    {
        const uint32_t* gt = (const uint32_t*)(table + (size_t)b * 12 * NB);
        uint32_t* tw = (uint32_t*)tb;
        for (int i = threadIdx.x; i < 12 * NB / 4; i += 256) tw[i] = gt[i];
    }
    __syncthreads();

    const float4* s0 = (const float4*)(src + (size_t)b * 3 * HW);
    const float4* s1 = s0 + HW / 4;
    const float4* s2 = s1 + HW / 4;
    const float4* t0 = (const float4*)(tgt + (size_t)b * 3 * HW);
    const float4* t1 = t0 + HW / 4;
    const float4* t2 = t1 + HW / 4;
    const uint2* pc = (const uint2*)(C + (size_t)b * (HW / 4));
    const uint2* qc = (const uint2*)(mbs + (size_t)b * (HW / 4));
    float4* o0 = (float4*)(out + (size_t)b * 3 * HW);
    float4* o1 = o0 + HW / 4;
    float4* o2 = o1 + HW / 4;

    uint2 cw = pc[c];
    uint2 qw = qc[c];
    float4 xa0 = s0[2 * c], xb0 = s0[2 * c + 1];
    float4 xa1 = s1[2 * c], xb1 = s1[2 * c + 1];
    float4 xa2 = s2[2 * c], xb2 = s2[2 * c + 1];
    float4 ra0 = t0[2 * c], rb0 = t0[2 * c + 1];
    float4 ra1 = t1[2 * c], rb1 = t1[2 * c + 1];
    float4 ra2 = t2[2 * c], rb2 = t2[2 * c + 1];

    float4 oa0, oa1, oa2, ob0, ob1, ob2;
    proc4(cw.x, qw.x, xa0, xa1, xa2, ra0, ra1, ra2, tb, oa0, oa1, oa2);
    proc4(cw.y, qw.y, xb0, xb1, xb2, rb0, rb1, rb2, tb, ob0, ob1, ob2);

    o0[2 * c] = oa0; o0[2 * c + 1] = ob0;
    o1[2 * c] = oa1; o1[2 * c + 1] = ob1;
    o2[2 * c] = oa2; o2[2 * c + 1] = ob2;
}

extern "C" void kernel_launch(void* const* d_in, const int* in_sizes, int n_in,
                              void* d_out, int out_size, void* d_ws, size_t ws_size,
                              hipStream_t stream) {
    const float* src = (const float*)d_in[0];   // (16,3,512,512)
    const float* tgt = (const float*)d_in[1];
    const float* ms  = (const float*)d_in[2];   // (16,5,512,512)
    const float* mr  = (const float*)d_in[3];
    float* out = (float*)d_out;

    uint8_t* ws = (uint8_t*)d_ws;
    uint32_t* C   = (uint32_t*)(ws);                                   // 2*BB*HW bytes
    uint32_t* eh  = (uint32_t*)(ws + (size_t)2 * BB * HW);             // 2*BB*HW bytes
    uint32_t* mbs = (uint32_t*)(ws + (size_t)4 * BB * HW);             // BB*HW bytes
    int* hist     = (int*)(ws + (size_t)5 * BB * HW);                  // 2*BB*12*NB*4
    uint8_t* table = ws + (size_t)5 * BB * HW + (size_t)2 * BB * 12 * NB * 4;

    hipMemsetAsync(hist, 0, (size_t)2 * BB * 12 * NB * sizeof(int), stream);

    prep_hor_kernel<<<2 * BB * 64, 256, 0, stream>>>(ms, mr, (uint4*)C, (uint4*)eh);
    ver_kernel<<<2 * BB * (HH / 4) * (WW / 16) / 256, 256, 0, stream>>>(eh, C);
    blur_kernel<<<BB * (HW / 16) / 256, 256, 0, stream>>>(C, (uint4*)mbs);
    hist_kernel<<<2 * BB * HB, 256, 0, stream>>>(src, tgt, C, hist);
    table_kernel<<<BB * 4 * 3, NB, 0, stream>>>(hist, table);
    compose_kernel<<<BB * (HW / 8) / 256, 256, 0, stream>>>(src, tgt, C, mbs, table, out);
}

// Round 4
// 328.396 us; speedup vs baseline: 1.4831x; 1.0163x over previous
//
#include <hip/hip_runtime.h>
#include <stdint.h>

#define BB 16
#define HH 512
#define WW 512
#define HW (HH*WW)
#define NB 256

// C plane byte layout (one byte per pixel, [side*BB+b][HW]):
//   bits 0-1: e = mask[2]+mask[3]  (0,1,2)
//   bit  2  : mask[0] > 0   (lip)
//   bit  3  : mask[1] > 0   (skin)
//   bit  4  : mask[4] > 0
//   bits 5-6: m_se (0,1,2)  -- merged in by ver_kernel

__device__ __forceinline__ float denorm255(float x) {
    return fminf(fmaxf((x + 1.0f) * 0.5f, 0.0f), 1.0f) * 255.0f;
}
__device__ __forceinline__ float renorm_lut(int t) {
    return ((float)t / 255.0f) * 2.0f - 1.0f;
}
// byte-granular funnel shift: result byte j = byte (j+r) of (hi:lo), r in 0..3
__device__ __forceinline__ uint32_t alignb(uint32_t hi, uint32_t lo, int r) {
    return (uint32_t)(((((uint64_t)hi) << 32) | lo) >> (8 * r));
}

// ---- K1: fused prep + horizontal +-12 OR. Block = 8 rows; word-interleaved ownership. ----
// Thread (r=t>>5, c=t&31) owns word-columns {c, c+32, c+64, c+96} of row r.
// Every global load/store instruction is lane-contiguous.
__global__ void __launch_bounds__(256) prep_hor_kernel(
    const float* __restrict__ ms, const float* __restrict__ mr,
    uint32_t* __restrict__ C, uint32_t* __restrict__ eh)
{
    int blk  = blockIdx.x;                 // 0 .. 2*BB*64-1
    int side = blk >> 10;                  // BB*64 = 1024
    int rem  = blk & 1023;
    int b    = rem >> 6;
    int rg   = rem & 63;
    int r    = threadIdx.x >> 5;
    int c    = threadIdx.x & 31;
    int y    = (rg << 3) + r;

    const float* base = (side ? mr : ms) + (size_t)b * 5 * HW + (size_t)y * WW;

    // 20 coalesced float4 loads (lane-contiguous for each p,q)
    float4 v[5][4];
    #pragma unroll
    for (int p = 0; p < 5; p++) {
        const float4* pp = (const float4*)(base + (size_t)p * HW);
        #pragma unroll
        for (int q = 0; q < 4; q++) v[p][q] = pp[c + 32 * q];
    }

    __shared__ uint32_t sE[8][128];
    size_t plane = (size_t)(side * BB + b);
    uint32_t* Crow = C + plane * (HW / 4) + y * 128;
    #pragma unroll
    for (int q = 0; q < 4; q++) {
        uint32_t wc = 0;
        #pragma unroll
        for (int j = 0; j < 4; j++) {
            float a0 = (&v[0][q].x)[j];
            float a1 = (&v[1][q].x)[j];
            float a2 = (&v[2][q].x)[j];
            float a3 = (&v[3][q].x)[j];
            float a4 = (&v[4][q].x)[j];
            uint32_t e  = (uint32_t)(a2 + a3);              // exact 0/1/2
            uint32_t pb = (a0 > 0.f ? 4u : 0u) | (a1 > 0.f ? 8u : 0u)
                        | (a4 > 0.f ? 16u : 0u);
            wc |= (e | pb) << (8 * j);
        }
        Crow[c + 32 * q] = wc;             // coalesced dword store
        sE[r][c + 32 * q] = wc & 0x03030303u;
    }
    __syncthreads();

    uint32_t* Erow = eh + plane * (HW / 4) + y * 128;
    #pragma unroll
    for (int q = 0; q < 4; q++) {
        int w = c + 32 * q;
        uint32_t arr[7];
        #pragma unroll
        for (int i = 0; i < 7; i++) {
            int idx = w - 3 + i;
            arr[i] = (idx >= 0 && idx < 128) ? sE[r][idx] : 0u;
        }
        uint32_t acc = arr[3];
        #pragma unroll
        for (int s = 1; s <= 12; s++) {
            int a = s >> 2, rr = s & 3;
            uint32_t vp, vm;
            if (rr == 0) {
                vp = arr[3 + a];
                vm = arr[3 - a];
            } else {
                vp = alignb(arr[3 + a + 1], arr[3 + a], rr);
                int am = (s + 3) >> 2;
                vm = alignb(arr[3 - am + 1], arr[3 - am], 4 - rr);
            }
            acc |= vp | vm;
        }
        Erow[w] = acc;                     // coalesced dword store
    }
}

// ---- K2: vertical OR over +-12 rows, map 3->2, AND with m1, pack into C bits 5-6 ----
__global__ void __launch_bounds__(256) ver_kernel(
    const uint32_t* __restrict__ eh, uint32_t* __restrict__ C)
{
    int t   = blockIdx.x * 256 + threadIdx.x;
    int sb  = t >> 12;            // 128 ygroups * 32 chunks per plane
    int rem = t & 4095;
    int yg  = rem >> 5;
    int ck  = rem & 31;
    int y0  = yg << 2;
    const uint4* P = (const uint4*)(eh + (size_t)sb * (HW / 4));
    auto R = [&](int y) -> uint4 {
        uint4 z = {0, 0, 0, 0};
        if (y < 0 || y >= HH) return z;
        return P[y * 32 + ck];
    };
    uint4 core = {0, 0, 0, 0};
    #pragma unroll
    for (int yy = -9; yy <= 12; yy++) {
        uint4 r = R(y0 + yy);
        core.x |= r.x; core.y |= r.y; core.z |= r.z; core.w |= r.w;
    }
    uint4 b0 = R(y0 - 12), b1 = R(y0 - 11), b2 = R(y0 - 10);
    uint4 a0 = R(y0 + 13), a1 = R(y0 + 14), a2 = R(y0 + 15);

    uint4* C4 = (uint4*)(C + (size_t)sb * (HW / 4));
    #pragma unroll
    for (int i = 0; i < 4; i++) {
        uint4 v = core;
        if (i == 0) { v.x|=b0.x|b1.x|b2.x; v.y|=b0.y|b1.y|b2.y; v.z|=b0.z|b1.z|b2.z; v.w|=b0.w|b1.w|b2.w; }
        if (i == 1) { v.x|=b1.x|b2.x|a0.x; v.y|=b1.y|b2.y|a0.y; v.z|=b1.z|b2.z|a0.z; v.w|=b1.w|b2.w|a0.w; }
        if (i == 2) { v.x|=b2.x|a0.x|a1.x; v.y|=b2.y|a0.y|a1.y; v.z|=b2.z|a0.z|a1.z; v.w|=b2.w|a0.w|a1.w; }
        if (i == 3) { v.x|=a0.x|a1.x|a2.x; v.y|=a0.y|a1.y|a2.y; v.z|=a0.z|a1.z|a2.z; v.w|=a0.w|a1.w|a2.w; }
        int idx = (y0 + i) * 32 + ck;
        uint4 cw = C4[idx];
        #pragma unroll
        for (int q = 0; q < 4; q++) {
            uint32_t vv = (&v.x)[q];
            uint32_t cc = (&cw.x)[q];
            uint32_t t3 = vv & (vv >> 1) & 0x01010101u;   // byte==3 detector
            vv -= t3;                                      // map 3 -> 2
            uint32_t m1b = (cc >> 3) & 0x01010101u;        // skin mask bits
            vv &= m1b * 255u;                              // select where m1
            (&cw.x)[q] = cc | (vv << 5);
        }
        C4[idx] = cw;
    }
}

// ---- K3: 5x5 box sum of m_se (src side), 16 px per thread ----
__global__ void __launch_bounds__(256) blur_kernel(
    const uint32_t* __restrict__ C, uint4* __restrict__ mbs)
{
    int t = blockIdx.x * 256 + threadIdx.x;
    int b = t >> 14;
    int rem = t & 16383;
    int y = rem >> 5;
    int c = rem & 31;
    const uint32_t* P = C + (size_t)b * (HW / 4);   // src side plane
    int c4 = c << 2;
    uint32_t s[6] = {0u, 0u, 0u, 0u, 0u, 0u};
    #pragma unroll
    for (int dy = -2; dy <= 2; dy++) {
        int yy = y + dy;
        if (yy < 0 || yy >= HH) continue;
        const uint32_t* rp = P + yy * 128;
        uint32_t l = (c > 0)  ? rp[c4 - 1] : 0u;
        uint4 m = *((const uint4*)(rp + c4));
        uint32_t rr = (c < 31) ? rp[c4 + 4] : 0u;
        s[0] += (l   >> 5) & 0x03030303u;
        s[1] += (m.x >> 5) & 0x03030303u;
        s[2] += (m.y >> 5) & 0x03030303u;
        s[3] += (m.z >> 5) & 0x03030303u;
        s[4] += (m.w >> 5) & 0x03030303u;
        s[5] += (rr  >> 5) & 0x03030303u;
    }
    uint4 o;
    #pragma unroll
    for (int k = 0; k < 4; k++) {
        uint32_t v = s[k + 1];
        v += alignb(s[k + 1], s[k],     2);
        v += alignb(s[k + 1], s[k],     3);
        v += alignb(s[k + 2], s[k + 1], 1);
        v += alignb(s[k + 2], s[k + 1], 2);
        (&o.x)[k] = v;
    }
    mbs[t] = o;
}

// ---- K4: 12 weighted histograms per (batch, side); 2 LDS replicas (per wave-pair) ----
#define HB 32
__device__ __forceinline__ void hist4(int* h, uint32_t cw,
                                      float4 v0, float4 v1, float4 v2)
{
    float d0[4] = {denorm255(v0.x), denorm255(v0.y), denorm255(v0.z), denorm255(v0.w)};
    float d1[4] = {denorm255(v1.x), denorm255(v1.y), denorm255(v1.z), denorm255(v1.w)};
    float d2[4] = {denorm255(v2.x), denorm255(v2.y), denorm255(v2.z), denorm255(v2.w)};
    #pragma unroll
    for (int j = 0; j < 4; j++) {
        uint32_t pb = (cw >> (8 * j)) & 0xFFu;
        if (pb & 8u) {
            atomicAdd(&h[0 * NB + min((int)d0[j], 255)], 1);
            atomicAdd(&h[1 * NB + min((int)d1[j], 255)], 1);
            atomicAdd(&h[2 * NB + min((int)d2[j], 255)], 1);
        }
        if (pb & 16u) {
            atomicAdd(&h[3 * NB + min((int)d0[j], 255)], 1);
            atomicAdd(&h[4 * NB + min((int)d1[j], 255)], 1);
            atomicAdd(&h[5 * NB + min((int)d2[j], 255)], 1);
        }
        if (pb & 4u) {
            atomicAdd(&h[6 * NB + min((int)d0[j], 255)], 1);
            atomicAdd(&h[7 * NB + min((int)d1[j], 255)], 1);
            atomicAdd(&h[8 * NB + min((int)d2[j], 255)], 1);
        }
        int mei = (int)((pb >> 5) & 3u);
        if (mei) {
            float fm = (float)mei;
            atomicAdd(&h[ 9 * NB + min((int)(d0[j] * fm), 255)], mei);
            atomicAdd(&h[10 * NB + min((int)(d1[j] * fm), 255)], mei);
            atomicAdd(&h[11 * NB + min((int)(d2[j] * fm), 255)], mei);
        }
    }
}

__global__ void __launch_bounds__(256) hist_kernel(
    const float* __restrict__ src, const float* __restrict__ tgt,
    const uint32_t* __restrict__ C, int* __restrict__ hist)
{
    int bs  = blockIdx.x / HB;
    int blk = blockIdx.x % HB;
    int b = bs >> 1, side = bs & 1;
    const float* img = (side ? tgt : src) + (size_t)b * 3 * HW;
    const float4* i0 = (const float4*)(img);
    const float4* i1 = (const float4*)(img + HW);
    const float4* i2 = (const float4*)(img + 2 * (size_t)HW);
    const uint2* pc = (const uint2*)(C + (size_t)(side * BB + b) * (HW / 4));

    __shared__ int h[2][12 * NB];
    int* hw = h[threadIdx.x >> 7];          // replica per wave-pair
    for (int i = threadIdx.x; i < 2 * 12 * NB; i += 256) ((int*)h)[i] = 0;
    __syncthreads();

    for (int c = blk * 256 + threadIdx.x; c < HW / 8; c += HB * 256) {
        uint2 cw = pc[c];
        float4 a0 = i0[2 * c], b0 = i0[2 * c + 1];
        float4 a1 = i1[2 * c], b1 = i1[2 * c + 1];
        float4 a2 = i2[2 * c], b2 = i2[2 * c + 1];
        hist4(hw, cw.x, a0, a1, a2);
        hist4(hw, cw.y, b0, b1, b2);
    }
    __syncthreads();
    int* gh = hist + (size_t)bs * 12 * NB;
    for (int i = threadIdx.x; i < 12 * NB; i += 256) {
        int s = h[0][i] + h[1][i];
        if (s) atomicAdd(&gh[i], s);
    }
}

// ---- K5: cdf + searchsorted -> 256-entry LUT per (b, region, channel) ----
__global__ void __launch_bounds__(NB) table_kernel(
    const int* __restrict__ hist, uint8_t* __restrict__ table)
{
    int idx = blockIdx.x;               // (b*4+rg)*3+c, 192 blocks
    int c = idx % 3; int rest = idx / 3; int rg = rest & 3; int b = rest >> 2;
    const int* hs = hist + ((size_t)((b * 2 + 0) * 4 + rg) * 3 + c) * NB;
    const int* hr = hist + ((size_t)((b * 2 + 1) * 4 + rg) * 3 + c) * NB;
    __shared__ int a[NB];
    __shared__ float cr[NB];
    int t = threadIdx.x;

    a[t] = hs[t];
    __syncthreads();
    for (int off = 1; off < NB; off <<= 1) {
        int v = (t >= off) ? a[t - off] : 0;
        __syncthreads();
        a[t] += v;
        __syncthreads();
    }
    int totS = a[NB - 1];
    int cumS = a[t];
    __syncthreads();

    a[t] = hr[t];
    __syncthreads();
    for (int off = 1; off < NB; off <<= 1) {
        int v = (t >= off) ? a[t - off] : 0;
        __syncthreads();
        a[t] += v;
        __syncthreads();
    }
    int totR = a[NB - 1];
    cr[t] = (float)a[t] / fmaxf((float)totR, 1e-6f);
    float v = (float)cumS / fmaxf((float)totS, 1e-6f);
    __syncthreads();

    int cnt = 0;
    for (int j = 0; j < NB; j++) cnt += (cr[j] < v) ? 1 : 0;
    table[(size_t)idx * NB + t] = (uint8_t)min(cnt, 255);
}

// ---- K6: final composite, 8 px per thread, single-shot ----
__device__ __forceinline__ void proc4(uint32_t cw, uint32_t qw,
    float4 x0, float4 x1, float4 x2, float4 r0, float4 r1, float4 r2,
    const uint8_t* tb, float4& o0, float4& o1, float4& o2)
{
    float X0[4] = {x0.x, x0.y, x0.z, x0.w};
    float X1[4] = {x1.x, x1.y, x1.z, x1.w};
    float X2[4] = {x2.x, x2.y, x2.z, x2.w};
    float R0[4] = {r0.x, r0.y, r0.z, r0.w};
    float R1[4] = {r1.x, r1.y, r1.z, r1.w};
    float R2[4] = {r2.x, r2.y, r2.z, r2.w};
    #pragma unroll
    for (int j = 0; j < 4; j++) {
        uint32_t pb = (cw >> (8 * j)) & 0xFFu;
        float q = (float)((qw >> (8 * j)) & 0xFFu);
        float m0f = (float)((pb >> 2) & 1u);
        float m1f = (float)((pb >> 3) & 1u);
        float m4f = (float)((pb >> 4) & 1u);
        float fm  = (float)((pb >> 5) & 3u);
        float d0 = denorm255(X0[j]), d1 = denorm255(X1[j]), d2 = denorm255(X2[j]);
        float p0 = X0[j], p1 = X1[j], p2 = X2[j];
        {
            float e0 = renorm_lut(tb[0 * NB + min((int)(d0 * m1f), 255)]);
            float e1 = renorm_lut(tb[1 * NB + min((int)(d1 * m1f), 255)]);
            float e2 = renorm_lut(tb[2 * NB + min((int)(d2 * m1f), 255)]);
            p0 = (1.0f - m1f) * p0 + m1f * e0;
            p1 = (1.0f - m1f) * p1 + m1f * e1;
            p2 = (1.0f - m1f) * p2 + m1f * e2;
        }
        {
            float e0 = renorm_lut(tb[3 * NB + min((int)(d0 * m4f), 255)]);
            float e1 = renorm_lut(tb[4 * NB + min((int)(d1 * m4f), 255)]);
            float e2 = renorm_lut(tb[5 * NB + min((int)(d2 * m4f), 255)]);
            p0 = (1.0f - m4f) * p0 + m4f * e0;
            p1 = (1.0f - m4f) * p1 + m4f * e1;
            p2 = (1.0f - m4f) * p2 + m4f * e2;
        }
        {
            float e0 = renorm_lut(tb[6 * NB + min((int)(d0 * m0f), 255)]);
            float e1 = renorm_lut(tb[7 * NB + min((int)(d1 * m0f), 255)]);
            float e2 = renorm_lut(tb[8 * NB + min((int)(d2 * m0f), 255)]);
            p0 = (1.0f - m0f) * p0 + m0f * e0;
            p1 = (1.0f - m0f) * p1 + m0f * e1;
            p2 = (1.0f - m0f) * p2 + m0f * e2;
        }
        {
            float mb = (q * (1.0f / 25.0f)) * fm;
            float e0 = renorm_lut(tb[ 9 * NB + min((int)(d0 * fm), 255)]);
            float e1 = renorm_lut(tb[10 * NB + min((int)(d1 * fm), 255)]);
            float e2 = renorm_lut(tb[11 * NB + min((int)(d2 * fm), 255)]);
            p0 = (1.0f - mb) * p0 + mb * e0;
            p1 = (1.0f - mb) * p1 + mb * e1;
            p2 = (1.0f - mb) * p2 + mb * e2;
        }
        float a = 0.3f * m1f;
        p0 = (1.0f - a) * p0 + a * R0[j];
        p1 = (1.0f - a) * p1 + a * R1[j];
        p2 = (1.0f - a) * p2 + a * R2[j];
        a = 0.8f * fm;
        p0 = (1.0f - a) * p0 + a * R0[j];
        p1 = (1.0f - a) * p1 + a * R1[j];
        p2 = (1.0f - a) * p2 + a * R2[j];
        a = 0.1f * m0f;
        p0 = (1.0f - a) * p0 + a * R0[j];
        p1 = (1.0f - a) * p1 + a * R1[j];
        p2 = (1.0f - a) * p2 + a * R2[j];
        (&o0.x)[j] = p0; (&o1.x)[j] = p1; (&o2.x)[j] = p2;
    }
}

__global__ void __launch_bounds__(256) compose_kernel(
    const float* __restrict__ src, const float* __restrict__ tgt,
    const uint32_t* __restrict__ C, const uint32_t* __restrict__ mbs,
    const uint8_t* __restrict__ table, float* __restrict__ out)
{
    int t = blockIdx.x * 256 + threadIdx.x;   // 16 * 32768 / 256 = 2048 blocks
    int b = t >> 15;
    int c = t & 32767;                        // uint2 / float4-pair index

    __shared__ uint8_t tb[12 * NB];
    {
        const uint32_t* gt = (const uint32_t*)(table + (size_t)b * 12 * NB);
        uint32_t* tw = (uint32_t*)tb;
        for (int i = threadIdx.x; i < 12 * NB / 4; i += 256) tw[i] = gt[i];
    }
    __syncthreads();

    const float4* s0 = (const float4*)(src + (size_t)b * 3 * HW);
    const float4* s1 = s0 + HW / 4;
    const float4* s2 = s1 + HW / 4;
    const float4* t0 = (const float4*)(tgt + (size_t)b * 3 * HW);
    const float4* t1 = t0 + HW / 4;
    const float4* t2 = t1 + HW / 4;
    const uint2* pc = (const uint2*)(C + (size_t)b * (HW / 4));
    const uint2* qc = (const uint2*)(mbs + (size_t)b * (HW / 4));
    float4* o0 = (float4*)(out + (size_t)b * 3 * HW);
    float4* o1 = o0 + HW / 4;
    float4* o2 = o1 + HW / 4;

    uint2 cw = pc[c];
    uint2 qw = qc[c];
    float4 xa0 = s0[2 * c], xb0 = s0[2 * c + 1];
    float4 xa1 = s1[2 * c], xb1 = s1[2 * c + 1];
    float4 xa2 = s2[2 * c], xb2 = s2[2 * c + 1];
    float4 ra0 = t0[2 * c], rb0 = t0[2 * c + 1];
    float4 ra1 = t1[2 * c], rb1 = t1[2 * c + 1];
    float4 ra2 = t2[2 * c], rb2 = t2[2 * c + 1];

    float4 oa0, oa1, oa2, ob0, ob1, ob2;
    proc4(cw.x, qw.x, xa0, xa1, xa2, ra0, ra1, ra2, tb, oa0, oa1, oa2);
    proc4(cw.y, qw.y, xb0, xb1, xb2, rb0, rb1, rb2, tb, ob0, ob1, ob2);

    o0[2 * c] = oa0; o0[2 * c + 1] = ob0;
    o1[2 * c] = oa1; o1[2 * c + 1] = ob1;
    o2[2 * c] = oa2; o2[2 * c + 1] = ob2;
}

extern "C" void kernel_launch(void* const* d_in, const int* in_sizes, int n_in,
                              void* d_out, int out_size, void* d_ws, size_t ws_size,
                              hipStream_t stream) {
    const float* src = (const float*)d_in[0];   // (16,3,512,512)
    const float* tgt = (const float*)d_in[1];
    const float* ms  = (const float*)d_in[2];   // (16,5,512,512)
    const float* mr  = (const float*)d_in[3];
    float* out = (float*)d_out;

    uint8_t* ws = (uint8_t*)d_ws;
    uint32_t* C   = (uint32_t*)(ws);                                   // 2*BB*HW bytes
    uint32_t* eh  = (uint32_t*)(ws + (size_t)2 * BB * HW);             // 2*BB*HW bytes
    uint32_t* mbs = (uint32_t*)(ws + (size_t)4 * BB * HW);             // BB*HW bytes
    int* hist     = (int*)(ws + (size_t)5 * BB * HW);                  // 2*BB*12*NB*4
    uint8_t* table = ws + (size_t)5 * BB * HW + (size_t)2 * BB * 12 * NB * 4;

    hipMemsetAsync(hist, 0, (size_t)2 * BB * 12 * NB * sizeof(int), stream);

    prep_hor_kernel<<<2 * BB * 64, 256, 0, stream>>>(ms, mr, C, eh);
    ver_kernel<<<2 * BB * (HH / 4) * (WW / 16) / 256, 256, 0, stream>>>(eh, C);
    blur_kernel<<<BB * (HW / 16) / 256, 256, 0, stream>>>(C, (uint4*)mbs);
    hist_kernel<<<2 * BB * HB, 256, 0, stream>>>(src, tgt, C, hist);
    table_kernel<<<BB * 4 * 3, NB, 0, stream>>>(hist, table);
    compose_kernel<<<BB * (HW / 8) / 256, 256, 0, stream>>>(src, tgt, C, mbs, table, out);
}